// Round 1
// baseline (539.082 us; speedup 1.0000x reference)
//
#include <hip/hip_runtime.h>
#include <hip/hip_bf16.h>

#define B   512
#define C   512
#define HW  240
#define E   128
#define XD  640   // C + E
#define G3  1536  // 3*C

typedef short  s8v  __attribute__((ext_vector_type(8)));
typedef float  f4v  __attribute__((ext_vector_type(4)));

__device__ __forceinline__ float fast_tanh(float x) {
    float ex = __expf(2.0f * x);
    return (ex - 1.0f) * __builtin_amdgcn_rcpf(ex + 1.0f);
}
__device__ __forceinline__ float fast_sigmoid(float x) {
    return __builtin_amdgcn_rcpf(1.0f + __expf(-x));
}
__device__ __forceinline__ unsigned short f2bf(float x) {
    return __builtin_bit_cast(unsigned short, __float2bfloat16(x));
}

// ---------------- attention: emition -> softmax -> context -> x(bf16) -------
__global__ __launch_bounds__(512) void attn_kernel(
    const float* __restrict__ prev_hidden,       // [B, C]
    const float* __restrict__ conv_feats,        // [B, C, HW]
    const float* __restrict__ conv_feats_origin, // [B, C, HW]
    const float* __restrict__ cur_emb,           // [B, E]
    const float* __restrict__ score_w,           // [C]
    float* __restrict__ alpha_out,               // [HW, B]
    unsigned short* __restrict__ x_bf16)         // [B, XD] bf16
{
    const int b = blockIdx.x;
    const int t = threadIdx.x;
    const int lane = t & 63;
    const int w = t >> 6;

    __shared__ float sw_s[C];
    __shared__ float ph_s[C];
    __shared__ float tmp[512];
    __shared__ float af[HW];
    __shared__ float red[8];

    for (int i = t; i < C; i += 512) {
        sw_s[i] = score_w[i];
        ph_s[i] = prev_hidden[b * C + i];
    }
    __syncthreads();

    // pass 1: emition[h] = sum_c tanh(cf[b,c,h] + ph[c]) * sw[c]
    // threads t<480: h = t % 240, c-half = t / 240 (256 c's each)
    float acc = 0.f;
    if (t < 480) {
        const int h = t % HW;
        const int c0 = (t / HW) * 256;
        const float* cf = conv_feats + (size_t)b * C * HW + h;
        #pragma unroll 8
        for (int c = 0; c < 256; ++c) {
            float v = cf[(size_t)(c0 + c) * HW];
            acc += fast_tanh(v + ph_s[c0 + c]) * sw_s[c0 + c];
        }
    }
    tmp[t] = acc;
    __syncthreads();

    float e = -1e30f;
    if (t < HW) e = tmp[t] + tmp[t + HW];

    // block max
    float m = e;
    #pragma unroll
    for (int off = 32; off >= 1; off >>= 1) m = fmaxf(m, __shfl_xor(m, off));
    if (lane == 0) red[w] = m;
    __syncthreads();
    m = red[0];
    #pragma unroll
    for (int i = 1; i < 8; ++i) m = fmaxf(m, red[i]);

    float p = (t < HW) ? __expf(e - m) : 0.f;
    float s = p;
    #pragma unroll
    for (int off = 32; off >= 1; off >>= 1) s += __shfl_xor(s, off);
    __syncthreads();  // red reuse
    if (lane == 0) red[w] = s;
    __syncthreads();
    s = red[0];
    #pragma unroll
    for (int i = 1; i < 8; ++i) s += red[i];
    float inv = __builtin_amdgcn_rcpf(s);

    if (t < HW) {
        float a = p * inv;
        af[t] = a;
        alpha_out[t * B + b] = a;   // alpha.T layout [HW, B]
    }
    __syncthreads();

    // pass 2: context[c] = sum_h cfo[b,c,h] * alpha[h]; one c per thread
    {
        const float4* row = (const float4*)(conv_feats_origin +
                                            (size_t)b * C * HW + (size_t)t * HW);
        float ctx = 0.f;
        #pragma unroll 4
        for (int h4 = 0; h4 < HW / 4; ++h4) {
            float4 v = row[h4];
            ctx += v.x * af[4 * h4]     + v.y * af[4 * h4 + 1]
                 + v.z * af[4 * h4 + 2] + v.w * af[4 * h4 + 3];
        }
        x_bf16[(size_t)b * XD + t] = f2bf(ctx);
    }
    if (t < E) x_bf16[(size_t)b * XD + C + t] = f2bf(cur_emb[b * E + t]);
}

// ---------------- f32 -> bf16 convert (vectorized x4) ------------------------
__global__ void cvt4_kernel(const float4* __restrict__ src,
                            ushort4* __restrict__ dst, int n4)
{
    int i = blockIdx.x * blockDim.x + threadIdx.x;
    if (i < n4) {
        float4 v = src[i];
        ushort4 o;
        o.x = f2bf(v.x); o.y = f2bf(v.y); o.z = f2bf(v.z); o.w = f2bf(v.w);
        dst[i] = o;
    }
}

// ---------------- GEMM: G[b,j] = sum_k A[b,k] * W[j,k] + bias[j] -------------
// z=0: gi = x @ w_ih^T (K=640)    z=1: gh = h @ w_hh^T (K=512)
__global__ __launch_bounds__(256) void gemm_kernel(
    const unsigned short* __restrict__ x,
    const unsigned short* __restrict__ hprev,
    const unsigned short* __restrict__ wih,
    const unsigned short* __restrict__ whh,
    const float* __restrict__ b_ih, const float* __restrict__ b_hh,
    float* __restrict__ gi, float* __restrict__ gh)
{
    const int z = blockIdx.z;
    const unsigned short* Amat = z ? hprev : x;
    const unsigned short* Wmat = z ? whh : wih;
    const float* bias = z ? b_hh : b_ih;
    float* out = z ? gh : gi;
    const int K = z ? C : XD;

    const int b0 = blockIdx.x * 64;
    const int j0 = blockIdx.y * 64;

    __shared__ alignas(16) unsigned short As[64][40]; // padded: 40*2B row stride
    __shared__ alignas(16) unsigned short Ws[64][40];

    const int t = threadIdx.x, lane = t & 63, w = t >> 6;
    const int wm = w & 1, wn = w >> 1;          // 2x2 wave grid -> 32x32 each
    const int r = t >> 2, kq = t & 3;           // staging: row, k-quad
    const int q = lane >> 4, mm = lane & 15;    // fragment indices

    f4v z4 = {0.f, 0.f, 0.f, 0.f};
    f4v acc[2][2] = {{z4, z4}, {z4, z4}};

    for (int k0 = 0; k0 < K; k0 += 32) {
        *(s8v*)&As[r][kq * 8] =
            *(const s8v*)&Amat[(size_t)(b0 + r) * K + k0 + kq * 8];
        *(s8v*)&Ws[r][kq * 8] =
            *(const s8v*)&Wmat[(size_t)(j0 + r) * K + k0 + kq * 8];
        __syncthreads();

        s8v a0 = *(const s8v*)&As[wm * 32 + mm][q * 8];
        s8v a1 = *(const s8v*)&As[wm * 32 + 16 + mm][q * 8];
        s8v w0 = *(const s8v*)&Ws[wn * 32 + mm][q * 8];
        s8v w1 = *(const s8v*)&Ws[wn * 32 + 16 + mm][q * 8];

        acc[0][0] = __builtin_amdgcn_mfma_f32_16x16x32_bf16(a0, w0, acc[0][0], 0, 0, 0);
        acc[0][1] = __builtin_amdgcn_mfma_f32_16x16x32_bf16(a0, w1, acc[0][1], 0, 0, 0);
        acc[1][0] = __builtin_amdgcn_mfma_f32_16x16x32_bf16(a1, w0, acc[1][0], 0, 0, 0);
        acc[1][1] = __builtin_amdgcn_mfma_f32_16x16x32_bf16(a1, w1, acc[1][1], 0, 0, 0);
        __syncthreads();
    }

    #pragma unroll
    for (int mi = 0; mi < 2; ++mi)
        #pragma unroll
        for (int ni = 0; ni < 2; ++ni) {
            int jj = j0 + wn * 32 + ni * 16 + mm;   // col = lane&15
            float bv = bias[jj];
            #pragma unroll
            for (int rg = 0; rg < 4; ++rg) {
                int bi = b0 + wm * 32 + mi * 16 + q * 4 + rg; // row = quad*4+reg
                out[(size_t)bi * G3 + jj] = acc[mi][ni][rg] + bv;
            }
        }
}

// ---------------- GRU gates --------------------------------------------------
__global__ void gates_kernel(const float* __restrict__ gi,
                             const float* __restrict__ gh,
                             const float* __restrict__ hprev,
                             float* __restrict__ out)
{
    int idx = blockIdx.x * blockDim.x + threadIdx.x;
    if (idx >= B * C) return;
    int b = idx >> 9;
    int c = idx & 511;
    const float* gib = gi + (size_t)b * G3;
    const float* ghb = gh + (size_t)b * G3;
    float r  = fast_sigmoid(gib[c] + ghb[c]);
    float zz = fast_sigmoid(gib[c + C] + ghb[c + C]);
    float n  = fast_tanh(gib[c + 2 * C] + r * ghb[c + 2 * C]);
    out[idx] = (1.f - zz) * n + zz * hprev[idx];
}

// ---------------- launch -----------------------------------------------------
extern "C" void kernel_launch(void* const* d_in, const int* in_sizes, int n_in,
                              void* d_out, int out_size, void* d_ws, size_t ws_size,
                              hipStream_t stream)
{
    const float* prev_hidden = (const float*)d_in[0];
    const float* conv_feats  = (const float*)d_in[1];
    const float* cfo         = (const float*)d_in[2];
    const float* emb         = (const float*)d_in[3];
    const float* score_w     = (const float*)d_in[4];
    const float* w_ih        = (const float*)d_in[5];
    const float* w_hh        = (const float*)d_in[6];
    const float* b_ih        = (const float*)d_in[7];
    const float* b_hh        = (const float*)d_in[8];

    float* out       = (float*)d_out;
    float* alpha_out = out + B * C;           // output 1: alpha.T [HW, B]

    char* ws = (char*)d_ws;
    unsigned short* x_bf16 = (unsigned short*)(ws);             // 512*640*2 = 655360
    unsigned short* h_bf16 = (unsigned short*)(ws + 655360);    // 512*512*2 = 524288
    unsigned short* wih_bf = (unsigned short*)(ws + 1179648);   // 1536*640*2 = 1966080
    unsigned short* whh_bf = (unsigned short*)(ws + 3145728);   // 1536*512*2 = 1572864
    float* gi = (float*)(ws + 4718592);                         // 512*1536*4 = 3145728
    float* gh = (float*)(ws + 7864320);                         // 512*1536*4 = 3145728

    // weight / hidden converts (independent of attention)
    {
        int n4 = (G3 * XD) / 4;
        cvt4_kernel<<<(n4 + 255) / 256, 256, 0, stream>>>((const float4*)w_ih, (ushort4*)wih_bf, n4);
        n4 = (G3 * C) / 4;
        cvt4_kernel<<<(n4 + 255) / 256, 256, 0, stream>>>((const float4*)w_hh, (ushort4*)whh_bf, n4);
        n4 = (B * C) / 4;
        cvt4_kernel<<<(n4 + 255) / 256, 256, 0, stream>>>((const float4*)prev_hidden, (ushort4*)h_bf16, n4);
    }

    attn_kernel<<<B, 512, 0, stream>>>(prev_hidden, conv_feats, cfo, emb, score_w,
                                       alpha_out, x_bf16);

    gemm_kernel<<<dim3(8, 24, 2), 256, 0, stream>>>(x_bf16, h_bf16, wih_bf, whh_bf,
                                                    b_ih, b_hh, gi, gh);

    gates_kernel<<<(B * C + 255) / 256, 256, 0, stream>>>(gi, gh, prev_hidden, out);
}

// Round 2
// 520.620 us; speedup vs baseline: 1.0355x; 1.0355x over previous
//
#include <hip/hip_runtime.h>
#include <hip/hip_bf16.h>

#define B   512
#define C   512
#define HW  240
#define E   128
#define XD  640   // C + E
#define G3  1536  // 3*C

#define N4_WIH 245760   // 1536*640/4
#define N4_WHH 196608   // 1536*512/4
#define N4_H    65536   // 512*512/4

typedef short  s8v  __attribute__((ext_vector_type(8)));
typedef float  f4v  __attribute__((ext_vector_type(4)));

__device__ __forceinline__ float fast_tanh(float x) {
    float ex = __expf(2.0f * x);
    return (ex - 1.0f) * __builtin_amdgcn_rcpf(ex + 1.0f);
}
__device__ __forceinline__ float fast_sigmoid(float x) {
    return __builtin_amdgcn_rcpf(1.0f + __expf(-x));
}
__device__ __forceinline__ unsigned short f2bf(float x) {
    return __builtin_bit_cast(unsigned short, __float2bfloat16(x));
}

// ---------------- K1: emition partial sums ----------------------------------
// grid (B, 8): block computes partial[b][chunk][h] = sum over 64 c's of
// tanh(cf[b,c,h] + ph[c]) * sw[c].  Threads: cs=t/60 (c-subgroup of 16),
// i=t%60 (float4 along h). Fully coalesced float4 loads.
__global__ __launch_bounds__(256) void emition_kernel(
    const float* __restrict__ prev_hidden,   // [B, C]
    const float* __restrict__ conv_feats,    // [B, C, HW]
    const float* __restrict__ score_w,       // [C]
    float* __restrict__ partials)            // [B][8][HW]
{
    const int b = blockIdx.x;
    const int chunk = blockIdx.y;
    const int c0 = chunk * 64;
    const int t = threadIdx.x;

    __shared__ float ph_s[64], sw_s[64];
    __shared__ float4 red[4 * 60];

    if (t < 64) {
        ph_s[t] = prev_hidden[b * C + c0 + t];
        sw_s[t] = score_w[c0 + t];
    }
    __syncthreads();

    if (t < 240) {
        const int cs = t / 60;
        const int i  = t % 60;
        const float4* base =
            (const float4*)(conv_feats + ((size_t)(b * C + c0 + cs * 16)) * HW) + i;
        float4 acc = {0.f, 0.f, 0.f, 0.f};
        #pragma unroll
        for (int j = 0; j < 16; ++j) {
            float4 v = base[j * (HW / 4)];
            float ph = ph_s[cs * 16 + j];
            float sw = sw_s[cs * 16 + j];
            acc.x += fast_tanh(v.x + ph) * sw;
            acc.y += fast_tanh(v.y + ph) * sw;
            acc.z += fast_tanh(v.z + ph) * sw;
            acc.w += fast_tanh(v.w + ph) * sw;
        }
        red[cs * 60 + i] = acc;
    }
    __syncthreads();

    if (t < 60) {
        float4 a = red[t], b4 = red[60 + t], c4 = red[120 + t], d4 = red[180 + t];
        float4 s;
        s.x = a.x + b4.x + c4.x + d4.x;
        s.y = a.y + b4.y + c4.y + d4.y;
        s.z = a.z + b4.z + c4.z + d4.z;
        s.w = a.w + b4.w + c4.w + d4.w;
        ((float4*)(partials + ((size_t)b * 8 + chunk) * HW))[t] = s;
    }
}

// ---------------- K2: softmax over HW + emb copy -----------------------------
__global__ __launch_bounds__(256) void softmax_kernel(
    const float* __restrict__ partials,   // [B][8][HW]
    const float* __restrict__ cur_emb,    // [B, E]
    float* __restrict__ alpha_f32,        // [B, HW]
    float* __restrict__ alpha_out,        // [HW, B]
    unsigned short* __restrict__ x_bf16)  // [B, XD]
{
    const int b = blockIdx.x, t = threadIdx.x;
    const int lane = t & 63, w = t >> 6;
    __shared__ float red[4];

    float e = -1e30f;
    if (t < HW) {
        const float* p = partials + (size_t)b * 8 * HW + t;
        float s0 = 0.f;
        #pragma unroll
        for (int k = 0; k < 8; ++k) s0 += p[k * HW];
        e = s0;
    }
    float m = e;
    #pragma unroll
    for (int off = 32; off >= 1; off >>= 1) m = fmaxf(m, __shfl_xor(m, off));
    if (lane == 0) red[w] = m;
    __syncthreads();
    m = fmaxf(fmaxf(red[0], red[1]), fmaxf(red[2], red[3]));

    float p = (t < HW) ? __expf(e - m) : 0.f;
    float s = p;
    #pragma unroll
    for (int off = 32; off >= 1; off >>= 1) s += __shfl_xor(s, off);
    __syncthreads();
    if (lane == 0) red[w] = s;
    __syncthreads();
    s = red[0] + red[1] + red[2] + red[3];
    float inv = __builtin_amdgcn_rcpf(s);

    if (t < HW) {
        float a = p * inv;
        alpha_f32[b * HW + t] = a;
        alpha_out[(size_t)t * B + b] = a;
    }
    if (t < E) x_bf16[(size_t)b * XD + C + t] = f2bf(cur_emb[b * E + t]);
}

// ---------------- K3: context = cfo . alpha ---------------------------------
// grid (B, 8): block handles 64 c-rows. Each wave: 16 rows, 4 lanes/row,
// 64B-contiguous segments; shuffle-reduce across the 4 lanes.
__global__ __launch_bounds__(256) void context_kernel(
    const float* __restrict__ cfo,        // [B, C, HW]
    const float* __restrict__ alpha_f32,  // [B, HW]
    unsigned short* __restrict__ x_bf16)  // [B, XD]
{
    const int b = blockIdx.x, chunk = blockIdx.y, t = threadIdx.x;
    const int lane = t & 63, w = t >> 6;
    __shared__ float4 af4[60];
    if (t < 60) af4[t] = ((const float4*)(alpha_f32 + b * HW))[t];
    __syncthreads();

    const int r = chunk * 64 + w * 16 + (lane >> 2);  // c row
    const int q = lane & 3;
    const float4* row = (const float4*)(cfo + ((size_t)(b * C + r)) * HW);

    float acc = 0.f;
    #pragma unroll
    for (int k = 0; k < 15; ++k) {
        float4 v = row[q + 4 * k];
        float4 a = af4[q + 4 * k];
        acc += v.x * a.x + v.y * a.y + v.z * a.z + v.w * a.w;
    }
    acc += __shfl_xor(acc, 1);
    acc += __shfl_xor(acc, 2);
    if (q == 0) x_bf16[(size_t)b * XD + r] = f2bf(acc);
}

// ---------------- fused f32 -> bf16 converts --------------------------------
__global__ void cvt_all_kernel(const float4* __restrict__ wih,
                               const float4* __restrict__ whh,
                               const float4* __restrict__ h,
                               ushort4* __restrict__ wih_o,
                               ushort4* __restrict__ whh_o,
                               ushort4* __restrict__ h_o)
{
    int i = blockIdx.x * blockDim.x + threadIdx.x;
    const float4* src; ushort4* dst; int j;
    if (i < N4_WIH)                { src = wih; dst = wih_o; j = i; }
    else if (i < N4_WIH + N4_WHH)  { src = whh; dst = whh_o; j = i - N4_WIH; }
    else if (i < N4_WIH + N4_WHH + N4_H) { src = h; dst = h_o; j = i - N4_WIH - N4_WHH; }
    else return;
    float4 v = src[j];
    ushort4 o;
    o.x = f2bf(v.x); o.y = f2bf(v.y); o.z = f2bf(v.z); o.w = f2bf(v.w);
    dst[j] = o;
}

// ---------------- GEMM: G[b,j] = sum_k A[b,k] * W[j,k] + bias[j] -------------
// z=0: gi = x @ w_ih^T (K=640)    z=1: gh = h @ w_hh^T (K=512). BK=64.
__global__ __launch_bounds__(256) void gemm_kernel(
    const unsigned short* __restrict__ x,
    const unsigned short* __restrict__ hprev,
    const unsigned short* __restrict__ wih,
    const unsigned short* __restrict__ whh,
    const float* __restrict__ b_ih, const float* __restrict__ b_hh,
    float* __restrict__ gi, float* __restrict__ gh)
{
    const int z = blockIdx.z;
    const unsigned short* Amat = z ? hprev : x;
    const unsigned short* Wmat = z ? whh : wih;
    const float* bias = z ? b_hh : b_ih;
    float* out = z ? gh : gi;
    const int K = z ? C : XD;

    const int b0 = blockIdx.x * 64;
    const int j0 = blockIdx.y * 64;

    __shared__ alignas(16) unsigned short As[64][72]; // 144B row stride
    __shared__ alignas(16) unsigned short Ws[64][72];

    const int t = threadIdx.x, lane = t & 63, w = t >> 6;
    const int wm = w & 1, wn = w >> 1;
    const int r = t >> 2, kq = t & 3;
    const int q = lane >> 4, mm = lane & 15;

    f4v z4 = {0.f, 0.f, 0.f, 0.f};
    f4v acc[2][2] = {{z4, z4}, {z4, z4}};

    for (int k0 = 0; k0 < K; k0 += 64) {
        const unsigned short* ga = &Amat[(size_t)(b0 + r) * K + k0 + kq * 8];
        const unsigned short* gw = &Wmat[(size_t)(j0 + r) * K + k0 + kq * 8];
        s8v a_lo = *(const s8v*)ga;
        s8v a_hi = *(const s8v*)(ga + 32);
        s8v w_lo = *(const s8v*)gw;
        s8v w_hi = *(const s8v*)(gw + 32);
        __syncthreads();
        *(s8v*)&As[r][kq * 8]      = a_lo;
        *(s8v*)&As[r][kq * 8 + 32] = a_hi;
        *(s8v*)&Ws[r][kq * 8]      = w_lo;
        *(s8v*)&Ws[r][kq * 8 + 32] = w_hi;
        __syncthreads();

        #pragma unroll
        for (int kk = 0; kk < 2; ++kk) {
            s8v a0 = *(const s8v*)&As[wm * 32 + mm][kk * 32 + q * 8];
            s8v a1 = *(const s8v*)&As[wm * 32 + 16 + mm][kk * 32 + q * 8];
            s8v w0 = *(const s8v*)&Ws[wn * 32 + mm][kk * 32 + q * 8];
            s8v w1 = *(const s8v*)&Ws[wn * 32 + 16 + mm][kk * 32 + q * 8];
            acc[0][0] = __builtin_amdgcn_mfma_f32_16x16x32_bf16(a0, w0, acc[0][0], 0, 0, 0);
            acc[0][1] = __builtin_amdgcn_mfma_f32_16x16x32_bf16(a0, w1, acc[0][1], 0, 0, 0);
            acc[1][0] = __builtin_amdgcn_mfma_f32_16x16x32_bf16(a1, w0, acc[1][0], 0, 0, 0);
            acc[1][1] = __builtin_amdgcn_mfma_f32_16x16x32_bf16(a1, w1, acc[1][1], 0, 0, 0);
        }
    }

    #pragma unroll
    for (int mi = 0; mi < 2; ++mi)
        #pragma unroll
        for (int ni = 0; ni < 2; ++ni) {
            int jj = j0 + wn * 32 + ni * 16 + mm;
            float bv = bias[jj];
            #pragma unroll
            for (int rg = 0; rg < 4; ++rg) {
                int bi = b0 + wm * 32 + mi * 16 + q * 4 + rg;
                out[(size_t)bi * G3 + jj] = acc[mi][ni][rg] + bv;
            }
        }
}

// ---------------- GRU gates --------------------------------------------------
__global__ void gates_kernel(const float* __restrict__ gi,
                             const float* __restrict__ gh,
                             const float* __restrict__ hprev,
                             float* __restrict__ out)
{
    int idx = blockIdx.x * blockDim.x + threadIdx.x;
    if (idx >= B * C) return;
    int b = idx >> 9;
    int c = idx & 511;
    const float* gib = gi + (size_t)b * G3;
    const float* ghb = gh + (size_t)b * G3;
    float r  = fast_sigmoid(gib[c] + ghb[c]);
    float zz = fast_sigmoid(gib[c + C] + ghb[c + C]);
    float n  = fast_tanh(gib[c + 2 * C] + r * ghb[c + 2 * C]);
    out[idx] = (1.f - zz) * n + zz * hprev[idx];
}

// ---------------- launch -----------------------------------------------------
extern "C" void kernel_launch(void* const* d_in, const int* in_sizes, int n_in,
                              void* d_out, int out_size, void* d_ws, size_t ws_size,
                              hipStream_t stream)
{
    const float* prev_hidden = (const float*)d_in[0];
    const float* conv_feats  = (const float*)d_in[1];
    const float* cfo         = (const float*)d_in[2];
    const float* emb         = (const float*)d_in[3];
    const float* score_w     = (const float*)d_in[4];
    const float* w_ih        = (const float*)d_in[5];
    const float* w_hh        = (const float*)d_in[6];
    const float* b_ih        = (const float*)d_in[7];
    const float* b_hh        = (const float*)d_in[8];

    float* out       = (float*)d_out;
    float* alpha_out = out + B * C;   // output 1: alpha.T [HW, B]

    char* ws = (char*)d_ws;
    // partials (dead after K2) shares space with gi (written later by gemm)
    float* partials          = (float*)(ws);                    // 512*8*240*4 = 3,932,160
    float* gi                = (float*)(ws);                    // 512*1536*4  = 3,145,728 (overlap OK)
    float* gh                = (float*)(ws + 3932160);          // 3,145,728
    float* alpha_f32         = (float*)(ws + 7077888);          //   491,520
    unsigned short* x_bf16   = (unsigned short*)(ws + 7569408); //   655,360
    unsigned short* h_bf16   = (unsigned short*)(ws + 8224768); //   524,288
    unsigned short* wih_bf   = (unsigned short*)(ws + 8749056); // 1,966,080
    unsigned short* whh_bf   = (unsigned short*)(ws + 10715136);// 1,572,864  (end ~12.3 MB)

    {
        int n4 = N4_WIH + N4_WHH + N4_H;
        cvt_all_kernel<<<(n4 + 255) / 256, 256, 0, stream>>>(
            (const float4*)w_ih, (const float4*)w_hh, (const float4*)prev_hidden,
            (ushort4*)wih_bf, (ushort4*)whh_bf, (ushort4*)h_bf16);
    }

    emition_kernel<<<dim3(B, 8), 256, 0, stream>>>(prev_hidden, conv_feats, score_w, partials);
    softmax_kernel<<<B, 256, 0, stream>>>(partials, emb, alpha_f32, alpha_out, x_bf16);
    context_kernel<<<dim3(B, 8), 256, 0, stream>>>(cfo, alpha_f32, x_bf16);

    gemm_kernel<<<dim3(8, 24, 2), 256, 0, stream>>>(x_bf16, h_bf16, wih_bf, whh_bf,
                                                    b_ih, b_hh, gi, gh);

    gates_kernel<<<(B * C + 255) / 256, 256, 0, stream>>>(gi, gh, prev_hidden, out);
}

// Round 3
// 517.851 us; speedup vs baseline: 1.0410x; 1.0053x over previous
//
#include <hip/hip_runtime.h>
#include <hip/hip_bf16.h>

#define B   512
#define C   512
#define HW  240
#define E   128
#define XD  640   // C + E
#define G3  1536  // 3*C

typedef short  s8v  __attribute__((ext_vector_type(8)));
typedef float  f4v  __attribute__((ext_vector_type(4)));

__device__ __forceinline__ float fast_tanh(float x) {
    float ex = __expf(2.0f * x);
    return (ex - 1.0f) * __builtin_amdgcn_rcpf(ex + 1.0f);
}
__device__ __forceinline__ float fast_sigmoid(float x) {
    return __builtin_amdgcn_rcpf(1.0f + __expf(-x));
}
__device__ __forceinline__ unsigned short f2bf(float x) {
    return __builtin_bit_cast(unsigned short, __float2bfloat16(x));
}
__device__ __forceinline__ s8v pack8(float4 a, float4 b) {
    s8v o;
    o[0] = (short)f2bf(a.x); o[1] = (short)f2bf(a.y);
    o[2] = (short)f2bf(a.z); o[3] = (short)f2bf(a.w);
    o[4] = (short)f2bf(b.x); o[5] = (short)f2bf(b.y);
    o[6] = (short)f2bf(b.z); o[7] = (short)f2bf(b.w);
    return o;
}

// ---------------- K1: emition partial sums ----------------------------------
// grid (B, 8): block computes partial[b][chunk][h] = sum over 64 c's of
// tanh(cf[b,c,h] + ph[c]) * sw[c].
__global__ __launch_bounds__(256) void emition_kernel(
    const float* __restrict__ prev_hidden,   // [B, C]
    const float* __restrict__ conv_feats,    // [B, C, HW]
    const float* __restrict__ score_w,       // [C]
    float* __restrict__ partials)            // [B][8][HW]
{
    const int b = blockIdx.x;
    const int chunk = blockIdx.y;
    const int c0 = chunk * 64;
    const int t = threadIdx.x;

    __shared__ float ph_s[64], sw_s[64];
    __shared__ float4 red[4 * 60];

    if (t < 64) {
        ph_s[t] = prev_hidden[b * C + c0 + t];
        sw_s[t] = score_w[c0 + t];
    }
    __syncthreads();

    if (t < 240) {
        const int cs = t / 60;
        const int i  = t % 60;
        const float4* base =
            (const float4*)(conv_feats + ((size_t)(b * C + c0 + cs * 16)) * HW) + i;
        float4 acc = {0.f, 0.f, 0.f, 0.f};
        #pragma unroll
        for (int j = 0; j < 16; ++j) {
            float4 v = base[j * (HW / 4)];
            float ph = ph_s[cs * 16 + j];
            float sw = sw_s[cs * 16 + j];
            acc.x += fast_tanh(v.x + ph) * sw;
            acc.y += fast_tanh(v.y + ph) * sw;
            acc.z += fast_tanh(v.z + ph) * sw;
            acc.w += fast_tanh(v.w + ph) * sw;
        }
        red[cs * 60 + i] = acc;
    }
    __syncthreads();

    if (t < 60) {
        float4 a = red[t], b4 = red[60 + t], c4 = red[120 + t], d4 = red[180 + t];
        float4 s;
        s.x = a.x + b4.x + c4.x + d4.x;
        s.y = a.y + b4.y + c4.y + d4.y;
        s.z = a.z + b4.z + c4.z + d4.z;
        s.w = a.w + b4.w + c4.w + d4.w;
        ((float4*)(partials + ((size_t)b * 8 + chunk) * HW))[t] = s;
    }
}

// ---------------- K2: fused softmax (redundant per block) + context ----------
// grid (B, 8): every block recomputes softmax from partials (7.7 KB, cheap),
// then does 64 c-rows of context. chunk-0 block also writes alpha.T and the
// embedding slice of x.
__global__ __launch_bounds__(256) void ctx_softmax_kernel(
    const float* __restrict__ partials,   // [B][8][HW]
    const float* __restrict__ cfo,        // [B, C, HW]
    const float* __restrict__ cur_emb,    // [B, E]
    float* __restrict__ alpha_out,        // [HW, B]
    unsigned short* __restrict__ x_bf16)  // [B, XD]
{
    const int b = blockIdx.x, chunk = blockIdx.y, t = threadIdx.x;
    const int lane = t & 63, w = t >> 6;
    __shared__ float4 af4[60];
    __shared__ float red[4];

    // --- softmax from partials ---
    float e = -1e30f;
    if (t < HW) {
        const float* p = partials + (size_t)b * 8 * HW + t;
        float s0 = 0.f;
        #pragma unroll
        for (int k = 0; k < 8; ++k) s0 += p[k * HW];
        e = s0;
    }
    float m = e;
    #pragma unroll
    for (int off = 32; off >= 1; off >>= 1) m = fmaxf(m, __shfl_xor(m, off));
    if (lane == 0) red[w] = m;
    __syncthreads();
    m = fmaxf(fmaxf(red[0], red[1]), fmaxf(red[2], red[3]));

    float p = (t < HW) ? __expf(e - m) : 0.f;
    float s = p;
    #pragma unroll
    for (int off = 32; off >= 1; off >>= 1) s += __shfl_xor(s, off);
    __syncthreads();
    if (lane == 0) red[w] = s;
    __syncthreads();
    s = red[0] + red[1] + red[2] + red[3];
    float inv = __builtin_amdgcn_rcpf(s);
    float a = p * inv;

    if (t < HW) ((float*)af4)[t] = a;
    if (chunk == 0) {
        if (t < HW) alpha_out[(size_t)t * B + b] = a;
        if (t < E)  x_bf16[(size_t)b * XD + C + t] = f2bf(cur_emb[b * E + t]);
    }
    __syncthreads();

    // --- context: 64 c-rows, 4 lanes/row, 64B-contiguous segments ---
    const int r = chunk * 64 + w * 16 + (lane >> 2);
    const int q = lane & 3;
    const float4* row = (const float4*)(cfo + ((size_t)(b * C + r)) * HW);

    float acc = 0.f;
    #pragma unroll
    for (int k = 0; k < 15; ++k) {
        float4 v = row[q + 4 * k];
        float4 av = af4[q + 4 * k];
        acc += v.x * av.x + v.y * av.y + v.z * av.z + v.w * av.w;
    }
    acc += __shfl_xor(acc, 1);
    acc += __shfl_xor(acc, 2);
    if (q == 0) x_bf16[(size_t)b * XD + r] = f2bf(acc);
}

// ---------------- K3: GEMM with inline f32->bf16 staging ---------------------
// G[b,j] = sum_k A[b,k] * W[j,k] + bias[j]
// z=0: gi = x(bf16) @ w_ih(f32)^T, K=640.  z=1: gh = h(f32) @ w_hh(f32)^T, K=512.
__global__ __launch_bounds__(256) void gemm_kernel(
    const unsigned short* __restrict__ x,   // [B, XD] bf16
    const float* __restrict__ hprev,        // [B, C]  f32
    const float* __restrict__ wih,          // [G3, XD] f32
    const float* __restrict__ whh,          // [G3, C]  f32
    const float* __restrict__ b_ih, const float* __restrict__ b_hh,
    float* __restrict__ gi, float* __restrict__ gh)
{
    const int z = blockIdx.z;
    const float* Wmat = z ? whh : wih;
    const float* bias = z ? b_hh : b_ih;
    float* out = z ? gh : gi;
    const int K = z ? C : XD;

    const int b0 = blockIdx.x * 64;
    const int j0 = blockIdx.y * 64;

    __shared__ alignas(16) unsigned short As[64][72]; // 144B row stride
    __shared__ alignas(16) unsigned short Ws[64][72];

    const int t = threadIdx.x, lane = t & 63, w = t >> 6;
    const int wm = w & 1, wn = w >> 1;
    const int r = t >> 2, col0 = (t & 3) * 16;
    const int q = lane >> 4, mm = lane & 15;

    f4v z4 = {0.f, 0.f, 0.f, 0.f};
    f4v acc[2][2] = {{z4, z4}, {z4, z4}};

    for (int k0 = 0; k0 < K; k0 += 64) {
        s8v a0, a1, w0, w1;
        if (z) {
            const float4* pa = (const float4*)&hprev[(size_t)(b0 + r) * C + k0 + col0];
            float4 f0 = pa[0], f1 = pa[1], f2 = pa[2], f3 = pa[3];
            a0 = pack8(f0, f1); a1 = pack8(f2, f3);
        } else {
            const unsigned short* pa = &x[(size_t)(b0 + r) * XD + k0 + col0];
            a0 = *(const s8v*)pa; a1 = *(const s8v*)(pa + 8);
        }
        {
            const float4* pw = (const float4*)&Wmat[(size_t)(j0 + r) * K + k0 + col0];
            float4 f0 = pw[0], f1 = pw[1], f2 = pw[2], f3 = pw[3];
            w0 = pack8(f0, f1); w1 = pack8(f2, f3);
        }
        __syncthreads();
        *(s8v*)&As[r][col0]     = a0;
        *(s8v*)&As[r][col0 + 8] = a1;
        *(s8v*)&Ws[r][col0]     = w0;
        *(s8v*)&Ws[r][col0 + 8] = w1;
        __syncthreads();

        #pragma unroll
        for (int kk = 0; kk < 2; ++kk) {
            s8v av0 = *(const s8v*)&As[wm * 32 + mm][kk * 32 + q * 8];
            s8v av1 = *(const s8v*)&As[wm * 32 + 16 + mm][kk * 32 + q * 8];
            s8v wv0 = *(const s8v*)&Ws[wn * 32 + mm][kk * 32 + q * 8];
            s8v wv1 = *(const s8v*)&Ws[wn * 32 + 16 + mm][kk * 32 + q * 8];
            acc[0][0] = __builtin_amdgcn_mfma_f32_16x16x32_bf16(av0, wv0, acc[0][0], 0, 0, 0);
            acc[0][1] = __builtin_amdgcn_mfma_f32_16x16x32_bf16(av0, wv1, acc[0][1], 0, 0, 0);
            acc[1][0] = __builtin_amdgcn_mfma_f32_16x16x32_bf16(av1, wv0, acc[1][0], 0, 0, 0);
            acc[1][1] = __builtin_amdgcn_mfma_f32_16x16x32_bf16(av1, wv1, acc[1][1], 0, 0, 0);
        }
    }

    #pragma unroll
    for (int mi = 0; mi < 2; ++mi)
        #pragma unroll
        for (int ni = 0; ni < 2; ++ni) {
            int jj = j0 + wn * 32 + ni * 16 + mm;
            float bv = bias[jj];
            #pragma unroll
            for (int rg = 0; rg < 4; ++rg) {
                int bi = b0 + wm * 32 + mi * 16 + q * 4 + rg;
                out[(size_t)bi * G3 + jj] = acc[mi][ni][rg] + bv;
            }
        }
}

// ---------------- K4: GRU gates ----------------------------------------------
__global__ void gates_kernel(const float* __restrict__ gi,
                             const float* __restrict__ gh,
                             const float* __restrict__ hprev,
                             float* __restrict__ out)
{
    int idx = blockIdx.x * blockDim.x + threadIdx.x;
    if (idx >= B * C) return;
    int b = idx >> 9;
    int c = idx & 511;
    const float* gib = gi + (size_t)b * G3;
    const float* ghb = gh + (size_t)b * G3;
    float r  = fast_sigmoid(gib[c] + ghb[c]);
    float zz = fast_sigmoid(gib[c + C] + ghb[c + C]);
    float n  = fast_tanh(gib[c + 2 * C] + r * ghb[c + 2 * C]);
    out[idx] = (1.f - zz) * n + zz * hprev[idx];
}

// ---------------- launch -----------------------------------------------------
extern "C" void kernel_launch(void* const* d_in, const int* in_sizes, int n_in,
                              void* d_out, int out_size, void* d_ws, size_t ws_size,
                              hipStream_t stream)
{
    const float* prev_hidden = (const float*)d_in[0];
    const float* conv_feats  = (const float*)d_in[1];
    const float* cfo         = (const float*)d_in[2];
    const float* emb         = (const float*)d_in[3];
    const float* score_w     = (const float*)d_in[4];
    const float* w_ih        = (const float*)d_in[5];
    const float* w_hh        = (const float*)d_in[6];
    const float* b_ih        = (const float*)d_in[7];
    const float* b_hh        = (const float*)d_in[8];

    float* out       = (float*)d_out;
    float* alpha_out = out + B * C;   // output 1: alpha.T [HW, B]

    char* ws = (char*)d_ws;
    // partials (dead after K2) overlaps gi (written by K3)
    float* partials          = (float*)(ws);                    // 512*8*240*4 = 3,932,160
    float* gi                = (float*)(ws);                    // 512*1536*4  = 3,145,728
    float* gh                = (float*)(ws + 3932160);          // 3,145,728
    unsigned short* x_bf16   = (unsigned short*)(ws + 7077888); //   655,360 (end ~7.7 MB)

    emition_kernel<<<dim3(B, 8), 256, 0, stream>>>(prev_hidden, conv_feats, score_w, partials);
    ctx_softmax_kernel<<<dim3(B, 8), 256, 0, stream>>>(partials, cfo, emb, alpha_out, x_bf16);
    gemm_kernel<<<dim3(8, 24, 2), 256, 0, stream>>>(x_bf16, prev_hidden, w_ih, w_hh,
                                                    b_ih, b_hh, gi, gh);
    gates_kernel<<<(B * C + 255) / 256, 256, 0, stream>>>(gi, gh, prev_hidden, out);
}